// Round 8
// baseline (174.645 us; speedup 1.0000x reference)
//
#include <hip/hip_runtime.h>
#include <hip/hip_fp16.h>
#include <math.h>

// Problem constants (match reference)
#define BB 4096
#define LL 128
#define DD 64
#define VV 50257
#define TAB_ELEMS (VV * DD)   // 3,216,448 per table
#define RSTRIDE 72            // halves per staged row: 144 B = 9x16B (odd) -> conflict-free b128

// ---------------------------------------------------------------------------
// Kernel 1: stream-convert both fp32 tables to fp16 in workspace.
// ---------------------------------------------------------------------------
__global__ __launch_bounds__(256) void convert_tables_kernel(
    const float* __restrict__ mu, const float* __restrict__ feat,
    __half* __restrict__ out_mu, __half* __restrict__ out_feat)
{
    const int n4 = TAB_ELEMS / 4;
    for (int i = blockIdx.x * blockDim.x + threadIdx.x; i < n4;
         i += gridDim.x * blockDim.x) {
        const float4 m = ((const float4*)mu)[i];
        const float4 f = ((const float4*)feat)[i];
        union { __half2 h[2]; uint2 u; } pm, pf;
        pm.h[0] = __floats2half2_rn(m.x, m.y);
        pm.h[1] = __floats2half2_rn(m.z, m.w);
        pf.h[0] = __floats2half2_rn(f.x, f.y);
        pf.h[1] = __floats2half2_rn(f.z, f.w);
        ((uint2*)out_mu)[i]   = pm.u;
        ((uint2*)out_feat)[i] = pf.u;
    }
}

// ---------------------------------------------------------------------------
// Kernel 2: R4 skeleton + fp16 gathers + LDS row staging for the score pass
// (no second mu gather, no shfl butterflies in the score phase).
// ---------------------------------------------------------------------------
__device__ __forceinline__ float4 cvt_row4(uint2 raw) {
    const float2 f01 = __half22float2(*(const __half2*)&raw.x);
    const float2 f23 = __half22float2(*(const __half2*)&raw.y);
    return make_float4(f01.x, f01.y, f23.x, f23.y);
}

__global__ __launch_bounds__(256, 8) void softmax_attn_cos_kernel(
    const int* __restrict__ ids_a, const int* __restrict__ mask_a,
    const int* __restrict__ ids_b, const int* __restrict__ mask_b,
    const __half* __restrict__ mu_table, const __half* __restrict__ feat_table,
    float* __restrict__ out)
{
    __shared__ __half s_muh[2][LL * RSTRIDE];   // 36,864 B staged mu rows (raw fp16)
    __shared__ int    s_ids[2][LL];
    __shared__ float  s_msk[2][LL];
    __shared__ float4 s_q[2][16];
    __shared__ float4 s_qp[2][2][16];
    __shared__ float  s_sc[2][LL];
    __shared__ float4 s_op[2][2][16];
    __shared__ float  s_mean[2][DD];
    __shared__ float  s_sum[2];
    __shared__ int    s_nm[2];

    const int tid  = threadIdx.x;
    const int lane = tid & 63;
    const int wave = tid >> 6;        // 0..3
    const int side = wave >> 1;       // 0: a, 1: b
    const int wsub = wave & 1;        // which half of the 128 rows
    const int grp  = lane >> 4;       // 0..3 row subgroup
    const int c4   = lane & 15;       // 8-byte chunk index within a row
    const int b    = blockIdx.x;

    // ---- phase 1: ids + masks for both sides ----
    {
        const int si = tid >> 7;
        const int l  = tid & 127;
        const int* idp = si ? ids_b  : ids_a;
        const int* mp  = si ? mask_b : mask_a;
        s_ids[si][l] = idp[b * LL + l];
        s_msk[si][l] = (float)mp[b * LL + l];
    }
    __syncthreads();

    // ---- phase 2: gather unmasked mu rows (fp16, 1 line/row), accumulate q
    //      partials, stage raw rows in LDS for the score pass ----
    {
        float4 qp = make_float4(0.f, 0.f, 0.f, 0.f);
        #pragma unroll
        for (int it = 0; it < 16; ++it) {
            const int r = wsub * 64 + it * 4 + grp;
            if (s_msk[side][r] > 0.5f) {
                const uint2 raw =
                    ((const uint2*)(mu_table + (size_t)s_ids[side][r] * DD))[c4];
                const float4 f = cvt_row4(raw);
                qp.x += f.x; qp.y += f.y; qp.z += f.z; qp.w += f.w;
                ((uint2*)(&s_muh[side][r * RSTRIDE]))[c4] = raw;
            }
        }
        #pragma unroll
        for (int off = 16; off <= 32; off <<= 1) {   // sum the 4 row-groups
            qp.x += __shfl_xor(qp.x, off, 64);
            qp.y += __shfl_xor(qp.y, off, 64);
            qp.z += __shfl_xor(qp.z, off, 64);
            qp.w += __shfl_xor(qp.w, off, 64);
        }
        if (lane < 16) s_qp[side][wsub][c4] = qp;
    }
    __syncthreads();

    // ---- q = masked mean + nm count (waves 0/1, one per side) ----
    if (tid < 128) {
        const int si = tid >> 6;
        const int dd = tid & 63;
        float mv = s_msk[si][dd] + s_msk[si][dd + 64];
        #pragma unroll
        for (int off = 32; off; off >>= 1) mv += __shfl_xor(mv, off, 64);
        if (dd == 0) s_nm[si] = (int)(mv + 0.5f);
        const float denom = fmaxf(mv, 1.0f);
        if (dd < 16) {
            float4 q0 = s_qp[si][0][dd], q1 = s_qp[si][1][dd];
            float4 q;
            q.x = (q0.x + q1.x) / denom; q.y = (q0.y + q1.y) / denom;
            q.z = (q0.z + q1.z) / denom; q.w = (q0.w + q1.w) / denom;
            s_q[si][dd] = q;
        }
    }
    __syncthreads();

    // ---- phase 3: scores — each thread dots ONE full staged row vs q.
    //      8 conflict-free ds_read_b128 + broadcast q reads; no shuffles. ----
    {
        const int ls = wsub * 64 + lane;   // row index within this thread's side
        float sc = -1e9f;
        if (s_msk[side][ls] > 0.5f) {
            const uint4*  rp = (const uint4*)(&s_muh[side][ls * RSTRIDE]);
            const float4* qv = (const float4*)(&s_q[side][0]);
            float acc = 0.f;
            #pragma unroll
            for (int j = 0; j < 8; ++j) {
                const uint4 raw = rp[j];            // 8 halves: cols 8j..8j+7
                const float2 c01 = __half22float2(*(const __half2*)&raw.x);
                const float2 c23 = __half22float2(*(const __half2*)&raw.y);
                const float2 c45 = __half22float2(*(const __half2*)&raw.z);
                const float2 c67 = __half22float2(*(const __half2*)&raw.w);
                const float4 qa = qv[2 * j], qb = qv[2 * j + 1];
                acc += c01.x * qa.x + c01.y * qa.y + c23.x * qa.z + c23.y * qa.w
                     + c45.x * qb.x + c45.y * qb.y + c67.x * qb.z + c67.y * qb.w;
            }
            sc = acc;
        }
        s_sc[side][ls] = sc;
    }
    __syncthreads();

    // ---- phase 4: softmax per side (waves with wsub==0) ----
    if (wsub == 0) {
        const float s1 = s_sc[side][lane], s2 = s_sc[side][lane + 64];
        float mx = fmaxf(s1, s2);
        #pragma unroll
        for (int off = 32; off; off >>= 1) mx = fmaxf(mx, __shfl_xor(mx, off, 64));
        const float e1 = expf(s1 - mx), e2 = expf(s2 - mx);
        s_sc[side][lane] = e1; s_sc[side][lane + 64] = e2;
        float sm = e1 + e2;
        #pragma unroll
        for (int off = 32; off; off >>= 1) sm += __shfl_xor(sm, off, 64);
        if (lane == 0) s_sum[side] = sm;
    }
    __syncthreads();

    // ---- phase 5: attn-weighted feat gather (fp16), mask-skip ----
    {
        const bool allm = (s_nm[side] == 0);
        float4 op = make_float4(0.f, 0.f, 0.f, 0.f);
        #pragma unroll
        for (int it = 0; it < 16; ++it) {
            const int r = wsub * 64 + it * 4 + grp;
            if (allm || s_msk[side][r] > 0.5f) {
                const float w = s_sc[side][r];
                const uint2 raw =
                    ((const uint2*)(feat_table + (size_t)s_ids[side][r] * DD))[c4];
                const float4 f = cvt_row4(raw);
                op.x = fmaf(f.x, w, op.x); op.y = fmaf(f.y, w, op.y);
                op.z = fmaf(f.z, w, op.z); op.w = fmaf(f.w, w, op.w);
            }
        }
        #pragma unroll
        for (int off = 16; off <= 32; off <<= 1) {
            op.x += __shfl_xor(op.x, off, 64);
            op.y += __shfl_xor(op.y, off, 64);
            op.z += __shfl_xor(op.z, off, 64);
            op.w += __shfl_xor(op.w, off, 64);
        }
        if (lane < 16) s_op[side][wsub][c4] = op;
    }
    __syncthreads();

    // ---- combine halves -> mean vectors ----
    if (tid < 32) {
        const int si = tid >> 4, cc = tid & 15;
        const float inv = 1.0f / s_sum[si];
        float4 o0 = s_op[si][0][cc], o1 = s_op[si][1][cc];
        float4 o;
        o.x = (o0.x + o1.x) * inv; o.y = (o0.y + o1.y) * inv;
        o.z = (o0.z + o1.z) * inv; o.w = (o0.w + o1.w) * inv;
        ((float4*)&s_mean[si][0])[cc] = o;
    }
    __syncthreads();

    // ---- cosine similarity * 5 (wave 0) ----
    if (tid < 64) {
        const float a = s_mean[0][tid], c = s_mean[1][tid];
        float dt = a * c, na = a * a, nb = c * c;
        #pragma unroll
        for (int off = 32; off; off >>= 1) {
            dt += __shfl_xor(dt, off, 64);
            na += __shfl_xor(na, off, 64);
            nb += __shfl_xor(nb, off, 64);
        }
        if (tid == 0) {
            const float denom = fmaxf(sqrtf(na), 1e-8f) * fmaxf(sqrtf(nb), 1e-8f);
            out[b] = 5.0f * dt / denom;
        }
    }
}

extern "C" void kernel_launch(void* const* d_in, const int* in_sizes, int n_in,
                              void* d_out, int out_size, void* d_ws, size_t ws_size,
                              hipStream_t stream) {
    const int*   ids_a  = (const int*)d_in[0];
    const int*   mask_a = (const int*)d_in[1];
    const int*   ids_b  = (const int*)d_in[2];
    const int*   mask_b = (const int*)d_in[3];
    const float* mu     = (const float*)d_in[4];
    const float* feat   = (const float*)d_in[5];
    float* out = (float*)d_out;

    __half* ws_mu   = (__half*)d_ws;
    __half* ws_feat = ws_mu + TAB_ELEMS;   // needs 2*TAB_ELEMS*2 B ~ 12.3 MB of ws

    convert_tables_kernel<<<1024, 256, 0, stream>>>(mu, feat, ws_mu, ws_feat);
    softmax_attn_cos_kernel<<<BB, 256, 0, stream>>>(
        ids_a, mask_a, ids_b, mask_b, ws_mu, ws_feat, out);
}

// Round 9
// 123.194 us; speedup vs baseline: 1.4176x; 1.4176x over previous
//
#include <hip/hip_runtime.h>
#include <hip/hip_fp16.h>
#include <math.h>

// Problem constants (match reference)
#define BB 4096
#define LL 128
#define DD 64
#define VV 50257
#define TAB_ELEMS (VV * DD)   // 3,216,448 per table

typedef _Float16 h2_t __attribute__((ext_vector_type(2)));

// fp16x2 dot-accumulate: one v_dot2_f32_f16 where available.
__device__ __forceinline__ float dot2acc(unsigned a, unsigned b, float c) {
#if __has_builtin(__builtin_amdgcn_fdot2)
    return __builtin_amdgcn_fdot2(__builtin_bit_cast(h2_t, a),
                                  __builtin_bit_cast(h2_t, b), c, false);
#else
    const float2 fa = __half22float2(*(const __half2*)&a);
    const float2 fb = __half22float2(*(const __half2*)&b);
    return fmaf(fa.x, fb.x, fmaf(fa.y, fb.y, c));
#endif
}

__device__ __forceinline__ float4 cvt_chunk(uint2 raw) {   // 4 halves -> 4 floats
    const float2 f01 = __half22float2(*(const __half2*)&raw.x);
    const float2 f23 = __half22float2(*(const __half2*)&raw.y);
    return make_float4(f01.x, f01.y, f23.x, f23.y);
}

__device__ __forceinline__ unsigned pack_h2(float a, float b) {
    union { __half2 h; unsigned u; } p;
    p.h = __floats2half2_rn(a, b);
    return p.u;
}

// ---------------------------------------------------------------------------
// Kernel 1: stream-convert both fp32 tables to fp16 in workspace.
// ---------------------------------------------------------------------------
__global__ __launch_bounds__(256) void convert_tables_kernel(
    const float* __restrict__ mu, const float* __restrict__ feat,
    __half* __restrict__ out_mu, __half* __restrict__ out_feat)
{
    const int n4 = TAB_ELEMS / 4;
    for (int i = blockIdx.x * blockDim.x + threadIdx.x; i < n4;
         i += gridDim.x * blockDim.x) {
        const float4 m = ((const float4*)mu)[i];
        const float4 f = ((const float4*)feat)[i];
        uint2 pm, pf;
        pm.x = pack_h2(m.x, m.y); pm.y = pack_h2(m.z, m.w);
        pf.x = pack_h2(f.x, f.y); pf.y = pack_h2(f.z, f.w);
        ((uint2*)out_mu)[i]   = pm;
        ((uint2*)out_feat)[i] = pf;
    }
}

// ---------------------------------------------------------------------------
// Kernel 2: R4 skeleton; mu held in regs (uint2 v[16] = 32 VGPRs, fp16) so
// there are only TWO gather passes; feat prefetched during the score phase;
// scores via v_dot2_f32_f16. Feat loaded for ALL rows -> no allm special case.
// ---------------------------------------------------------------------------
__global__ __launch_bounds__(256, 6) void softmax_attn_cos_kernel(
    const int* __restrict__ ids_a, const int* __restrict__ mask_a,
    const int* __restrict__ ids_b, const int* __restrict__ mask_b,
    const __half* __restrict__ mu_table, const __half* __restrict__ feat_table,
    float* __restrict__ out)
{
    __shared__ int      s_ids[2][LL];
    __shared__ float    s_msk[2][LL];
    __shared__ unsigned s_qh[2][32];      // q packed as 32 half2
    __shared__ float4   s_qp[2][2][16];
    __shared__ float    s_sc[2][LL];
    __shared__ float4   s_op[2][2][16];
    __shared__ float    s_mean[2][DD];
    __shared__ float    s_sum[2];

    const int tid  = threadIdx.x;
    const int lane = tid & 63;
    const int wave = tid >> 6;        // 0..3
    const int side = wave >> 1;       // 0: a, 1: b
    const int wsub = wave & 1;        // which half of the 128 rows
    const int grp  = lane >> 4;       // 0..3 row subgroup
    const int c4   = lane & 15;       // 8-byte chunk (4 halves) within a row
    const int b    = blockIdx.x;

    // ---- phase 1: ids + masks for both sides ----
    {
        const int si = tid >> 7;
        const int l  = tid & 127;
        const int* idp = si ? ids_b  : ids_a;
        const int* mp  = si ? mask_b : mask_a;
        s_ids[si][l] = idp[b * LL + l];
        s_msk[si][l] = (float)mp[b * LL + l];
    }
    __syncthreads();

    // ---- phase 2: gather unmasked mu rows into held regs + q partials ----
    uint2 v[16];
    unsigned kept = 0;
    {
        float4 qp = make_float4(0.f, 0.f, 0.f, 0.f);
        #pragma unroll
        for (int it = 0; it < 16; ++it) {
            const int r = wsub * 64 + it * 4 + grp;
            if (s_msk[side][r] > 0.5f) {
                kept |= (1u << it);
                v[it] = ((const uint2*)(mu_table + (size_t)s_ids[side][r] * DD))[c4];
                const float4 f = cvt_chunk(v[it]);
                qp.x += f.x; qp.y += f.y; qp.z += f.z; qp.w += f.w;
            } else {
                v[it] = make_uint2(0u, 0u);
            }
        }
        #pragma unroll
        for (int off = 16; off <= 32; off <<= 1) {   // sum the 4 row-groups
            qp.x += __shfl_xor(qp.x, off, 64);
            qp.y += __shfl_xor(qp.y, off, 64);
            qp.z += __shfl_xor(qp.z, off, 64);
            qp.w += __shfl_xor(qp.w, off, 64);
        }
        if (lane < 16) s_qp[side][wsub][c4] = qp;
    }
    __syncthreads();

    // ---- q = masked mean (waves 0/1, one per side); store as half2 ----
    if (tid < 128) {
        const int si = tid >> 6;
        const int dd = tid & 63;
        float mv = s_msk[si][dd] + s_msk[si][dd + 64];
        #pragma unroll
        for (int off = 32; off; off >>= 1) mv += __shfl_xor(mv, off, 64);
        const float denom = fmaxf(mv, 1.0f);
        if (dd < 16) {
            const float4 q0 = s_qp[si][0][dd], q1 = s_qp[si][1][dd];
            const float qx = (q0.x + q1.x) / denom, qy = (q0.y + q1.y) / denom;
            const float qz = (q0.z + q1.z) / denom, qw = (q0.w + q1.w) / denom;
            s_qh[si][2 * dd]     = pack_h2(qx, qy);
            s_qh[si][2 * dd + 1] = pack_h2(qz, qw);
        }
    }
    __syncthreads();

    // ---- phase 3: scores from held regs (v_dot2) + prefetch feat into v[] ----
    {
        const uint2 qq = ((const uint2*)&s_qh[side][0])[c4];  // this chunk's q
        #pragma unroll
        for (int it = 0; it < 16; ++it) {
            const int r = wsub * 64 + it * 4 + grp;
            float p = dot2acc(v[it].x, qq.x, 0.f);
            p = dot2acc(v[it].y, qq.y, p);
            // issue feat load early (consumed in phase 5, after softmax barrier)
            const uint2 nf =
                ((const uint2*)(feat_table + (size_t)s_ids[side][r] * DD))[c4];
            #pragma unroll
            for (int off = 1; off <= 8; off <<= 1)
                p += __shfl_xor(p, off, 64);         // reduce within 16-lane group
            if (c4 == 0) s_sc[side][r] = ((kept >> it) & 1u) ? p : -1e9f;
            v[it] = nf;
        }
    }
    __syncthreads();

    // ---- phase 4: softmax per side (waves with wsub==0) ----
    if (wsub == 0) {
        const float s1 = s_sc[side][lane], s2 = s_sc[side][lane + 64];
        float mx = fmaxf(s1, s2);
        #pragma unroll
        for (int off = 32; off; off >>= 1) mx = fmaxf(mx, __shfl_xor(mx, off, 64));
        const float e1 = expf(s1 - mx), e2 = expf(s2 - mx);
        s_sc[side][lane] = e1; s_sc[side][lane + 64] = e2;
        float sm = e1 + e2;
        #pragma unroll
        for (int off = 32; off; off >>= 1) sm += __shfl_xor(sm, off, 64);
        if (lane == 0) s_sum[side] = sm;
    }
    __syncthreads();

    // ---- phase 5: attn-weighted sum from held feat regs ----
    {
        float4 op = make_float4(0.f, 0.f, 0.f, 0.f);
        #pragma unroll
        for (int it = 0; it < 16; ++it) {
            const int r = wsub * 64 + it * 4 + grp;
            const float w  = s_sc[side][r];   // 0 for masked rows (or 1 if all-masked)
            const float4 f = cvt_chunk(v[it]);
            op.x = fmaf(f.x, w, op.x); op.y = fmaf(f.y, w, op.y);
            op.z = fmaf(f.z, w, op.z); op.w = fmaf(f.w, w, op.w);
        }
        #pragma unroll
        for (int off = 16; off <= 32; off <<= 1) {
            op.x += __shfl_xor(op.x, off, 64);
            op.y += __shfl_xor(op.y, off, 64);
            op.z += __shfl_xor(op.z, off, 64);
            op.w += __shfl_xor(op.w, off, 64);
        }
        if (lane < 16) s_op[side][wsub][c4] = op;
    }
    __syncthreads();

    // ---- combine halves -> mean vectors ----
    if (tid < 32) {
        const int si = tid >> 4, cc = tid & 15;
        const float inv = 1.0f / s_sum[si];
        const float4 o0 = s_op[si][0][cc], o1 = s_op[si][1][cc];
        float4 o;
        o.x = (o0.x + o1.x) * inv; o.y = (o0.y + o1.y) * inv;
        o.z = (o0.z + o1.z) * inv; o.w = (o0.w + o1.w) * inv;
        ((float4*)&s_mean[si][0])[cc] = o;
    }
    __syncthreads();

    // ---- cosine similarity * 5 (wave 0) ----
    if (tid < 64) {
        const float a = s_mean[0][tid], c = s_mean[1][tid];
        float dt = a * c, na = a * a, nb = c * c;
        #pragma unroll
        for (int off = 32; off; off >>= 1) {
            dt += __shfl_xor(dt, off, 64);
            na += __shfl_xor(na, off, 64);
            nb += __shfl_xor(nb, off, 64);
        }
        if (tid == 0) {
            const float denom = fmaxf(sqrtf(na), 1e-8f) * fmaxf(sqrtf(nb), 1e-8f);
            out[b] = 5.0f * dt / denom;
        }
    }
}

extern "C" void kernel_launch(void* const* d_in, const int* in_sizes, int n_in,
                              void* d_out, int out_size, void* d_ws, size_t ws_size,
                              hipStream_t stream) {
    const int*   ids_a  = (const int*)d_in[0];
    const int*   mask_a = (const int*)d_in[1];
    const int*   ids_b  = (const int*)d_in[2];
    const int*   mask_b = (const int*)d_in[3];
    const float* mu     = (const float*)d_in[4];
    const float* feat   = (const float*)d_in[5];
    float* out = (float*)d_out;

    __half* ws_mu   = (__half*)d_ws;
    __half* ws_feat = ws_mu + TAB_ELEMS;   // needs 2*TAB_ELEMS*2 B ~ 12.3 MB of ws

    convert_tables_kernel<<<1024, 256, 0, stream>>>(mu, feat, ws_mu, ws_feat);
    softmax_attn_cos_kernel<<<BB, 256, 0, stream>>>(
        ids_a, mask_a, ids_b, mask_b, ws_mu, ws_feat, out);
}

// Round 10
// 113.979 us; speedup vs baseline: 1.5323x; 1.0809x over previous
//
#include <hip/hip_runtime.h>
#include <hip/hip_fp16.h>
#include <math.h>

// Problem constants (match reference)
#define BB 4096
#define LL 128
#define DD 64
#define VV 50257
#define TAB_ELEMS (VV * DD)   // 3,216,448 per table

typedef _Float16 h2_t __attribute__((ext_vector_type(2)));

// fp16x2 dot-accumulate: one v_dot2_f32_f16 where available.
__device__ __forceinline__ float dot2acc(unsigned a, unsigned b, float c) {
#if __has_builtin(__builtin_amdgcn_fdot2)
    return __builtin_amdgcn_fdot2(__builtin_bit_cast(h2_t, a),
                                  __builtin_bit_cast(h2_t, b), c, false);
#else
    const float2 fa = __half22float2(*(const __half2*)&a);
    const float2 fb = __half22float2(*(const __half2*)&b);
    return fmaf(fa.x, fb.x, fmaf(fa.y, fb.y, c));
#endif
}

__device__ __forceinline__ float2 cvt2(unsigned raw) {
    return __half22float2(*(const __half2*)&raw);
}

__device__ __forceinline__ unsigned pack_h2(float a, float b) {
    union { __half2 h; unsigned u; } p;
    p.h = __floats2half2_rn(a, b);
    return p.u;
}

// ---------------------------------------------------------------------------
// Kernel 1: stream-convert both fp32 tables to fp16 in workspace.
// ---------------------------------------------------------------------------
__global__ __launch_bounds__(256) void convert_tables_kernel(
    const float* __restrict__ mu, const float* __restrict__ feat,
    __half* __restrict__ out_mu, __half* __restrict__ out_feat)
{
    const int n4 = TAB_ELEMS / 4;
    for (int i = blockIdx.x * blockDim.x + threadIdx.x; i < n4;
         i += gridDim.x * blockDim.x) {
        const float4 m = ((const float4*)mu)[i];
        const float4 f = ((const float4*)feat)[i];
        uint2 pm, pf;
        pm.x = pack_h2(m.x, m.y); pm.y = pack_h2(m.z, m.w);
        pf.x = pack_h2(f.x, f.y); pf.y = pack_h2(f.z, f.w);
        ((uint2*)out_mu)[i]   = pm;
        ((uint2*)out_feat)[i] = pf;
    }
}

// ---------------------------------------------------------------------------
// Kernel 2: R9 skeleton with 16 B/lane gathers: 8 lanes/row, 8 rows per
// wave-instruction -> 16 gather instructions per wave per side (was 32).
// mu held in uint4 v[8] (32 VGPRs); feat prefetched into v[] during scores.
// ---------------------------------------------------------------------------
__global__ __launch_bounds__(256, 6) void softmax_attn_cos_kernel(
    const int* __restrict__ ids_a, const int* __restrict__ mask_a,
    const int* __restrict__ ids_b, const int* __restrict__ mask_b,
    const __half* __restrict__ mu_table, const __half* __restrict__ feat_table,
    float* __restrict__ out)
{
    __shared__ int      s_ids[2][LL];
    __shared__ float    s_msk[2][LL];
    __shared__ unsigned s_qh[2][32];      // q packed as 32 half2
    __shared__ float4   s_qp[2][2][16];   // q partials: 16 float4 per side/half
    __shared__ float    s_sc[2][LL];
    __shared__ float4   s_op[2][2][16];
    __shared__ float    s_mean[2][DD];
    __shared__ float    s_sum[2];

    const int tid  = threadIdx.x;
    const int lane = tid & 63;
    const int wave = tid >> 6;        // 0..3
    const int side = wave >> 1;       // 0: a, 1: b
    const int wsub = wave & 1;        // which half of the 128 rows
    const int r8   = lane >> 3;       // 0..7 row subgroup
    const int c8   = lane & 7;        // 16-B chunk (8 halves) within a row
    const int b    = blockIdx.x;

    // ---- phase 1: ids + masks for both sides ----
    {
        const int si = tid >> 7;
        const int l  = tid & 127;
        const int* idp = si ? ids_b  : ids_a;
        const int* mp  = si ? mask_b : mask_a;
        s_ids[si][l] = idp[b * LL + l];
        s_msk[si][l] = (float)mp[b * LL + l];
    }
    __syncthreads();

    // ---- phase 2: gather unmasked mu rows (8 rows/instr) + q partials ----
    uint4 v[8];
    unsigned kept = 0;
    {
        float4 qa = make_float4(0.f, 0.f, 0.f, 0.f);
        float4 qb = make_float4(0.f, 0.f, 0.f, 0.f);
        #pragma unroll
        for (int it = 0; it < 8; ++it) {
            const int r = wsub * 64 + it * 8 + r8;
            if (s_msk[side][r] > 0.5f) {
                kept |= (1u << it);
                v[it] = ((const uint4*)(mu_table + (size_t)s_ids[side][r] * DD))[c8];
                const float2 f0 = cvt2(v[it].x), f1 = cvt2(v[it].y);
                const float2 f2 = cvt2(v[it].z), f3 = cvt2(v[it].w);
                qa.x += f0.x; qa.y += f0.y; qa.z += f1.x; qa.w += f1.y;
                qb.x += f2.x; qb.y += f2.y; qb.z += f3.x; qb.w += f3.y;
            } else {
                v[it] = make_uint4(0u, 0u, 0u, 0u);
            }
        }
        #pragma unroll
        for (int off = 8; off <= 32; off <<= 1) {   // sum the 8 row-groups
            qa.x += __shfl_xor(qa.x, off, 64); qa.y += __shfl_xor(qa.y, off, 64);
            qa.z += __shfl_xor(qa.z, off, 64); qa.w += __shfl_xor(qa.w, off, 64);
            qb.x += __shfl_xor(qb.x, off, 64); qb.y += __shfl_xor(qb.y, off, 64);
            qb.z += __shfl_xor(qb.z, off, 64); qb.w += __shfl_xor(qb.w, off, 64);
        }
        if (lane < 8) {
            s_qp[side][wsub][2 * c8]     = qa;
            s_qp[side][wsub][2 * c8 + 1] = qb;
        }
    }
    __syncthreads();

    // ---- q = masked mean (waves 0/1, one per side); store as half2 ----
    if (tid < 128) {
        const int si = tid >> 6;
        const int dd = tid & 63;
        float mv = s_msk[si][dd] + s_msk[si][dd + 64];
        #pragma unroll
        for (int off = 32; off; off >>= 1) mv += __shfl_xor(mv, off, 64);
        const float denom = fmaxf(mv, 1.0f);
        if (dd < 16) {
            const float4 q0 = s_qp[si][0][dd], q1 = s_qp[si][1][dd];
            const float qx = (q0.x + q1.x) / denom, qy = (q0.y + q1.y) / denom;
            const float qz = (q0.z + q1.z) / denom, qw = (q0.w + q1.w) / denom;
            s_qh[si][2 * dd]     = pack_h2(qx, qy);
            s_qh[si][2 * dd + 1] = pack_h2(qz, qw);
        }
    }
    __syncthreads();

    // ---- phase 3: scores from held regs (v_dot2) + prefetch feat into v[] ----
    {
        const uint4 qq = ((const uint4*)&s_qh[side][0])[c8];  // 8 q cols
        #pragma unroll
        for (int it = 0; it < 8; ++it) {
            const int r = wsub * 64 + it * 8 + r8;
            float p = dot2acc(v[it].x, qq.x, 0.f);
            p = dot2acc(v[it].y, qq.y, p);
            p = dot2acc(v[it].z, qq.z, p);
            p = dot2acc(v[it].w, qq.w, p);
            // issue feat load early (consumed in phase 5, after softmax barrier)
            const uint4 nf =
                ((const uint4*)(feat_table + (size_t)s_ids[side][r] * DD))[c8];
            #pragma unroll
            for (int off = 1; off <= 4; off <<= 1)
                p += __shfl_xor(p, off, 64);         // reduce within 8-lane group
            if (c8 == 0) s_sc[side][r] = ((kept >> it) & 1u) ? p : -1e9f;
            v[it] = nf;
        }
    }
    __syncthreads();

    // ---- phase 4: softmax per side (waves with wsub==0) ----
    if (wsub == 0) {
        const float s1 = s_sc[side][lane], s2 = s_sc[side][lane + 64];
        float mx = fmaxf(s1, s2);
        #pragma unroll
        for (int off = 32; off; off >>= 1) mx = fmaxf(mx, __shfl_xor(mx, off, 64));
        const float e1 = expf(s1 - mx), e2 = expf(s2 - mx);
        s_sc[side][lane] = e1; s_sc[side][lane + 64] = e2;
        float sm = e1 + e2;
        #pragma unroll
        for (int off = 32; off; off >>= 1) sm += __shfl_xor(sm, off, 64);
        if (lane == 0) s_sum[side] = sm;
    }
    __syncthreads();

    // ---- phase 5: attn-weighted sum from held feat regs ----
    {
        float4 oa = make_float4(0.f, 0.f, 0.f, 0.f);
        float4 ob = make_float4(0.f, 0.f, 0.f, 0.f);
        #pragma unroll
        for (int it = 0; it < 8; ++it) {
            const int r = wsub * 64 + it * 8 + r8;
            const float w = s_sc[side][r];   // 0 for masked rows (or uniform if all-masked)
            const float2 f0 = cvt2(v[it].x), f1 = cvt2(v[it].y);
            const float2 f2 = cvt2(v[it].z), f3 = cvt2(v[it].w);
            oa.x = fmaf(f0.x, w, oa.x); oa.y = fmaf(f0.y, w, oa.y);
            oa.z = fmaf(f1.x, w, oa.z); oa.w = fmaf(f1.y, w, oa.w);
            ob.x = fmaf(f2.x, w, ob.x); ob.y = fmaf(f2.y, w, ob.y);
            ob.z = fmaf(f3.x, w, ob.z); ob.w = fmaf(f3.y, w, ob.w);
        }
        #pragma unroll
        for (int off = 8; off <= 32; off <<= 1) {
            oa.x += __shfl_xor(oa.x, off, 64); oa.y += __shfl_xor(oa.y, off, 64);
            oa.z += __shfl_xor(oa.z, off, 64); oa.w += __shfl_xor(oa.w, off, 64);
            ob.x += __shfl_xor(ob.x, off, 64); ob.y += __shfl_xor(ob.y, off, 64);
            ob.z += __shfl_xor(ob.z, off, 64); ob.w += __shfl_xor(ob.w, off, 64);
        }
        if (lane < 8) {
            s_op[side][wsub][2 * c8]     = oa;
            s_op[side][wsub][2 * c8 + 1] = ob;
        }
    }
    __syncthreads();

    // ---- combine halves -> mean vectors ----
    if (tid < 32) {
        const int si = tid >> 4, cc = tid & 15;
        const float inv = 1.0f / s_sum[si];
        const float4 o0 = s_op[si][0][cc], o1 = s_op[si][1][cc];
        float4 o;
        o.x = (o0.x + o1.x) * inv; o.y = (o0.y + o1.y) * inv;
        o.z = (o0.z + o1.z) * inv; o.w = (o0.w + o1.w) * inv;
        ((float4*)&s_mean[si][0])[cc] = o;
    }
    __syncthreads();

    // ---- cosine similarity * 5 (wave 0) ----
    if (tid < 64) {
        const float a = s_mean[0][tid], c = s_mean[1][tid];
        float dt = a * c, na = a * a, nb = c * c;
        #pragma unroll
        for (int off = 32; off; off >>= 1) {
            dt += __shfl_xor(dt, off, 64);
            na += __shfl_xor(na, off, 64);
            nb += __shfl_xor(nb, off, 64);
        }
        if (tid == 0) {
            const float denom = fmaxf(sqrtf(na), 1e-8f) * fmaxf(sqrtf(nb), 1e-8f);
            out[b] = 5.0f * dt / denom;
        }
    }
}

extern "C" void kernel_launch(void* const* d_in, const int* in_sizes, int n_in,
                              void* d_out, int out_size, void* d_ws, size_t ws_size,
                              hipStream_t stream) {
    const int*   ids_a  = (const int*)d_in[0];
    const int*   mask_a = (const int*)d_in[1];
    const int*   ids_b  = (const int*)d_in[2];
    const int*   mask_b = (const int*)d_in[3];
    const float* mu     = (const float*)d_in[4];
    const float* feat   = (const float*)d_in[5];
    float* out = (float*)d_out;

    __half* ws_mu   = (__half*)d_ws;
    __half* ws_feat = ws_mu + TAB_ELEMS;   // needs 2*TAB_ELEMS*2 B ~ 12.3 MB of ws

    convert_tables_kernel<<<1024, 256, 0, stream>>>(mu, feat, ws_mu, ws_feat);
    softmax_attn_cos_kernel<<<BB, 256, 0, stream>>>(
        ids_a, mask_a, ids_b, mask_b, ws_mu, ws_feat, out);
}